// Round 2
// baseline (1809.591 us; speedup 1.0000x reference)
//
#include <hip/hip_runtime.h>
#include <stdint.h>

#define B_ 4
#define T_ 4096
#define D_ 1024
#define H_ 32
#define NX_ 12
#define NV_ 32
#define TT 8           // rows (b,t) per block in keys_kernel
#define NGRP 22        // 6 wx col-groups + 16 wv col-groups, 64 cols each
#define TAU 4e-5f      // |f32 acc| below this -> recompute dot in f64

// ---------------------------------------------------------------------------
// Kernel 1: logits -> packed keys (12b) and values (32b), sign-exact vs f64.
// ---------------------------------------------------------------------------
__global__ __launch_bounds__(256) void keys_kernel(
    const float* __restrict__ x, const float* __restrict__ wx,
    const float* __restrict__ wv, unsigned short* __restrict__ kxg,
    unsigned int* __restrict__ kvg)
{
  __shared__ float xs[TT][D_];                      // 32 KiB staged x rows
  __shared__ unsigned long long maskbuf[NGRP][TT];  // sign masks per group/row

  const int tid = threadIdx.x;
  const int wave = tid >> 6, lane = tid & 63;
  const long row0 = (long)blockIdx.x * TT;          // global row = b*T + t

  // stage 8 contiguous rows of x into LDS (float4 loads)
  const float4* xg = (const float4*)(x + row0 * D_);
  float4* xsv = (float4*)&xs[0][0];
#pragma unroll
  for (int k = 0; k < (TT * D_ / 4) / 256; ++k)
    xsv[tid + 256 * k] = xg[tid + 256 * k];
  __syncthreads();

  // each wave owns column-groups g = wave, wave+4, ...
  for (int g = wave; g < NGRP; g += 4) {
    const bool isx = (g < 6);
    const float* __restrict__ W = isx ? wx : wv;
    const int ldw = isx ? (H_ * NX_) : (H_ * NV_);
    const int col = (isx ? g * 64 : (g - 6) * 64) + lane;

    float acc[TT];
#pragma unroll
    for (int r = 0; r < TT; ++r) acc[r] = 0.f;

    for (int d = 0; d < D_; d += 4) {
      const float w0 = W[(d + 0) * ldw + col];
      const float w1 = W[(d + 1) * ldw + col];
      const float w2 = W[(d + 2) * ldw + col];
      const float w3 = W[(d + 3) * ldw + col];
#pragma unroll
      for (int r = 0; r < TT; ++r) {
        float4 xr = *(const float4*)&xs[r][d];
        float a = acc[r];
        a = fmaf(xr.x, w0, a);
        a = fmaf(xr.y, w1, a);
        a = fmaf(xr.z, w2, a);
        a = fmaf(xr.w, w3, a);
        acc[r] = a;
      }
    }

#pragma unroll
    for (int r = 0; r < TT; ++r) {
      bool pos = acc[r] > 0.f;
      if (fabsf(acc[r]) < TAU) {   // rare (~4e-5 of lanes): exact f64 redo
        double s = 0.0;
        for (int d = 0; d < D_; ++d)
          s = fma((double)xs[r][d], (double)W[d * ldw + col], s);
        pos = s > 0.0;
      }
      unsigned long long m = __ballot(pos);
      if (lane == 0) maskbuf[g][r] = m;
    }
  }
  __syncthreads();

  // assembly: thread -> (h, r); build 12-bit key from concatenated wx masks,
  // 32-bit value from wv masks; write [B,H,T] layouts.
  {
    const int h = tid >> 3, r = tid & 7;
    const long row = row0 + r;
    const int b = (int)(row >> 12);        // / T_
    const int t = (int)(row & (T_ - 1));
    const int bitpos = h * NX_;
    const int word = bitpos >> 6, off = bitpos & 63;
    unsigned long long v = maskbuf[word][r] >> off;
    if (off > 64 - NX_) v |= maskbuf[word + 1][r] << (64 - off);
    const unsigned int key = (unsigned int)(v & ((1u << NX_) - 1));
    const unsigned long long mv = maskbuf[6 + (h >> 1)][r];
    const unsigned int val = (h & 1) ? (unsigned int)(mv >> 32) : (unsigned int)mv;
    const long sidx = ((long)b * H_ + h) * T_ + t;
    kxg[sidx] = (unsigned short)key;
    kvg[sidx] = val;
  }
}

// ---------------------------------------------------------------------------
// Kernel 2: sequential associative-memory scan per (b,h) stream.
// Table lives in LDS; one lane runs the serial loop with 16-deep batching
// (DS pipe is in-order per wave, so read-before-write order is preserved).
// ---------------------------------------------------------------------------
#define CH 1024
#define UNR 16

__global__ __launch_bounds__(256) void scan_kernel(
    const unsigned short* __restrict__ kxg,
    const unsigned int* __restrict__ kvg,
    unsigned int* __restrict__ yg)
{
  __shared__ unsigned int table[1 << NX_];   // 16 KiB
  __shared__ unsigned int kbuf[CH], vbuf[CH], ybuf[CH];
  const int tid = threadIdx.x;
  const long base = (long)blockIdx.x * T_;   // stream s = b*H + h

#pragma unroll
  for (int i = 0; i < (1 << NX_) / 256; ++i) table[tid + 256 * i] = 0u;

  for (int c = 0; c < T_ / CH; ++c) {
    __syncthreads();
#pragma unroll
    for (int i = 0; i < CH / 256; ++i) {
      kbuf[tid + 256 * i] = kxg[base + c * CH + tid + 256 * i];
      vbuf[tid + 256 * i] = kvg[base + c * CH + tid + 256 * i];
    }
    __syncthreads();
    if (tid == 0) {
      for (int i = 0; i < CH; i += UNR) {
        unsigned int k[UNR], v[UNR], y[UNR];
#pragma unroll
        for (int u = 0; u < UNR; ++u) { k[u] = kbuf[i + u]; v[u] = vbuf[i + u]; }
#pragma unroll
        for (int u = 0; u < UNR; ++u) { y[u] = table[k[u]]; table[k[u]] = v[u]; }
#pragma unroll
        for (int u = 0; u < UNR; ++u) ybuf[i + u] = y[u];
      }
    }
    __syncthreads();
#pragma unroll
    for (int i = 0; i < CH / 256; ++i)
      yg[base + c * CH + tid + 256 * i] = ybuf[tid + 256 * i];
  }
}

// ---------------------------------------------------------------------------
// Kernel 3: expand recalled value bits into f32 embeddings.
// ---------------------------------------------------------------------------
__global__ __launch_bounds__(256) void out_kernel(
    const unsigned int* __restrict__ yg,
    const float* __restrict__ e0, const float* __restrict__ e1,
    float* __restrict__ out)
{
  const int tid = threadIdx.x;
  const int bt = blockIdx.x;                 // b*T + t
  const int b = bt >> 12, t = bt & (T_ - 1);
  const int h = tid >> 3;
  const unsigned int y = yg[((long)b * H_ + h) * T_ + t];
  const int d0 = tid * 4;
  const int vsh = (tid & 7) * 4;
  float4 o;
  o.x = ((y >> (vsh + 0)) & 1) ? e1[d0 + 0] : e0[d0 + 0];
  o.y = ((y >> (vsh + 1)) & 1) ? e1[d0 + 1] : e0[d0 + 1];
  o.z = ((y >> (vsh + 2)) & 1) ? e1[d0 + 2] : e0[d0 + 2];
  o.w = ((y >> (vsh + 3)) & 1) ? e1[d0 + 3] : e0[d0 + 3];
  *(float4*)&out[(long)bt * D_ + d0] = o;
}

// ---------------------------------------------------------------------------
extern "C" void kernel_launch(void* const* d_in, const int* in_sizes, int n_in,
                              void* d_out, int out_size, void* d_ws, size_t ws_size,
                              hipStream_t stream)
{
  const float* x  = (const float*)d_in[0];
  const float* wx = (const float*)d_in[1];
  const float* wv = (const float*)d_in[2];
  const float* e0 = (const float*)d_in[3];
  const float* e1 = (const float*)d_in[4];

  char* ws = (char*)d_ws;
  unsigned short* kxg = (unsigned short*)ws;              // 1 MiB  [B,H,T] u16
  unsigned int*   kvg = (unsigned int*)(ws + (1 << 20));  // 2 MiB  [B,H,T] u32
  unsigned int*   yg  = (unsigned int*)(ws + 3 * (1 << 20)); // 2 MiB [B,H,T] u32
  float* out = (float*)d_out;

  hipLaunchKernelGGL(keys_kernel, dim3(B_ * T_ / TT), dim3(256), 0, stream,
                     x, wx, wv, kxg, kvg);
  hipLaunchKernelGGL(scan_kernel, dim3(B_ * H_), dim3(256), 0, stream,
                     kxg, kvg, yg);
  hipLaunchKernelGGL(out_kernel, dim3(B_ * T_), dim3(256), 0, stream,
                     yg, e0, e1, out);
}

// Round 4
// 905.307 us; speedup vs baseline: 1.9989x; 1.9989x over previous
//
#include <hip/hip_runtime.h>
#include <stdint.h>

#define B_ 4
#define T_ 4096
#define D_ 1024
#define H_ 32
#define NX_ 12
#define NV_ 32
#define NCOL 1408          // 384 wx cols + 1024 wv cols
#define TAU 2e-4f          // |acc| below this -> recompute dot in f64 (~13 sigma)
#define BITW 88            // u16 words per bitmat row (1408/16)

typedef __attribute__((ext_vector_type(8))) short short8v;
typedef __attribute__((ext_vector_type(4))) float floatx4;

static __device__ __forceinline__ unsigned short bf16_rne(float f) {
  unsigned u = __float_as_uint(f);
  return (unsigned short)((u + 0x7FFFu + ((u >> 16) & 1u)) >> 16);
}
static __device__ __forceinline__ float bf16_to_f32(unsigned short h) {
  return __uint_as_float(((unsigned)h) << 16);
}

// MFMA 16x16x32 bf16 fragment k-permutation within each 32-k block:
// stored position p (0..31): group g = p>>3 holds k = {4g..4g+3, 16+4g..16+4g+3}
// (elems 0-3 = low half, 4-7 = high half of the 8-elem operand).

// ---------------------------------------------------------------------------
// Kernel 0: split W (f32) -> Wt_hi/Wt_lo bf16 [NCOL][1024], transposed and
// k-permuted for direct MFMA fragment loads.
// ---------------------------------------------------------------------------
__global__ __launch_bounds__(256) void wsplit_kernel(
    const float* __restrict__ wx, const float* __restrict__ wv,
    unsigned short* __restrict__ Wt_hi, unsigned short* __restrict__ Wt_lo)
{
  __shared__ float tile[64][65];
  const int tid = threadIdx.x;
  const int cb = blockIdx.x % (NCOL / 64);   // col tile (22)
  const int kb = blockIdx.x / (NCOL / 64);   // k tile (16)
  const int c_local = tid & 63;
  const int c_glob = cb * 64 + c_local;

#pragma unroll
  for (int i = 0; i < 16; ++i) {
    const int k_local = (tid >> 6) + i * 4;
    const int k_glob = kb * 64 + k_local;
    const float v = (c_glob < 384) ? wx[k_glob * 384 + c_glob]
                                   : wv[k_glob * 1024 + (c_glob - 384)];
    tile[k_local][c_local] = v;
  }
  __syncthreads();

#pragma unroll
  for (int i = 0; i < 4; ++i) {
    const int q = (tid >> 6) * 4 + i;        // quad index 0..15
    const int k0 = q * 4;                    // local k base (multiple of 4)
    const int r = k0 & 31;
    const int g = (r < 16) ? (r >> 2) : ((r - 16) >> 2);
    const int half = (r < 16) ? 0 : 1;
    const int p = g * 8 + half * 4;          // permuted position in 32-block
    const long dst = (long)c_glob * 1024 + kb * 64 + (k0 & 32) + p;
    ushort4 hv, lv;
    float f0 = tile[k0 + 0][c_local], f1 = tile[k0 + 1][c_local];
    float f2 = tile[k0 + 2][c_local], f3 = tile[k0 + 3][c_local];
    hv.x = bf16_rne(f0); lv.x = bf16_rne(f0 - bf16_to_f32(hv.x));
    hv.y = bf16_rne(f1); lv.y = bf16_rne(f1 - bf16_to_f32(hv.y));
    hv.z = bf16_rne(f2); lv.z = bf16_rne(f2 - bf16_to_f32(hv.z));
    hv.w = bf16_rne(f3); lv.w = bf16_rne(f3 - bf16_to_f32(hv.w));
    *(ushort4*)&Wt_hi[dst] = hv;
    *(ushort4*)&Wt_lo[dst] = lv;
  }
}

// ---------------------------------------------------------------------------
// Kernel 1: S = x @ [wx|wv] via split-bf16 MFMA; emit sign bits to bitmat.
// 128x128 tile, BK=32, 4 waves (2x2), 4x4 16x16x32 frags per wave, 3 MFMA
// per frag pair (hh, hl, lh). XOR-swizzled LDS slots: slot(row,g)=g^((row>>1)&3).
// ---------------------------------------------------------------------------
__global__ __launch_bounds__(256) void gemm_kernel(
    const float* __restrict__ x,
    const unsigned short* __restrict__ Wt_hi,
    const unsigned short* __restrict__ Wt_lo,
    const float* __restrict__ wx, const float* __restrict__ wv,
    unsigned short* __restrict__ bitmat)
{
  __shared__ unsigned short Ah[4096], Al[4096], Bh[4096], Bl[4096];

  const int tid = threadIdx.x;
  const int wid = tid >> 6, lane = tid & 63;
  const int wr = wid >> 1, wc = wid & 1;
  const int bx = blockIdx.x % 11;            // N tile (fast -> A-panel sharing)
  const int by = blockIdx.x / 11;            // M tile

  floatx4 acc[4][4];
#pragma unroll
  for (int i = 0; i < 4; ++i)
#pragma unroll
    for (int j = 0; j < 4; ++j) acc[i][j] = (floatx4)0.f;

  const int arow = tid >> 1;                 // A-stage: row 0..127
  const int ahalf = tid & 1;                 // k half (0: k0..15, 1: k16..31)

  for (int ks = 0; ks < 32; ++ks) {
    __syncthreads();   // previous iteration's readers done

    // ---- stage A: f32 load -> bf16 hi/lo split -> swizzled ds_write ----
    {
      const float4* xp = (const float4*)(x + ((long)(by * 128 + arow)) * 1024
                                           + ks * 32 + ahalf * 16);
      float4 f[4];
#pragma unroll
      for (int g = 0; g < 4; ++g) f[g] = xp[g];
#pragma unroll
      for (int g = 0; g < 4; ++g) {
        const int sl = g ^ ((arow >> 1) & 3);
        const int idx = arow * 32 + sl * 8 + ahalf * 4;
        ushort4 hv, lv;
        hv.x = bf16_rne(f[g].x); lv.x = bf16_rne(f[g].x - bf16_to_f32(hv.x));
        hv.y = bf16_rne(f[g].y); lv.y = bf16_rne(f[g].y - bf16_to_f32(hv.y));
        hv.z = bf16_rne(f[g].z); lv.z = bf16_rne(f[g].z - bf16_to_f32(hv.z));
        hv.w = bf16_rne(f[g].w); lv.w = bf16_rne(f[g].w - bf16_to_f32(hv.w));
        *(ushort4*)&Ah[idx] = hv;
        *(ushort4*)&Al[idx] = lv;
      }
    }

    // ---- stage B: global_load_lds (16B), global is pre-permuted ----
#pragma unroll
    for (int i = 0; i < 2; ++i) {
      const int c = wid * 64 + i * 256 + lane;     // chunk 0..511
      const int row = c >> 2, sl = c & 3;
      const int g = sl ^ ((row >> 1) & 3);
      const long src = ((long)(bx * 128 + row)) * 1024 + ks * 32 + g * 8;
      __builtin_amdgcn_global_load_lds(
          (const __attribute__((address_space(1))) unsigned int*)(Wt_hi + src),
          (__attribute__((address_space(3))) unsigned int*)&Bh[c * 8], 16, 0, 0);
      __builtin_amdgcn_global_load_lds(
          (const __attribute__((address_space(1))) unsigned int*)(Wt_lo + src),
          (__attribute__((address_space(3))) unsigned int*)&Bl[c * 8], 16, 0, 0);
    }

    __syncthreads();   // all staged data visible

    // ---- fragment loads (conflict-free b128) + 48 MFMA ----
    short8v ah[4], al[4], bh[4], bl[4];
    const int g = lane >> 4;
#pragma unroll
    for (int mi = 0; mi < 4; ++mi) {
      const int row = wr * 64 + mi * 16 + (lane & 15);
      const int off = row * 32 + (g ^ ((row >> 1) & 3)) * 8;
      ah[mi] = *(const short8v*)&Ah[off];
      al[mi] = *(const short8v*)&Al[off];
    }
#pragma unroll
    for (int nj = 0; nj < 4; ++nj) {
      const int row = wc * 64 + nj * 16 + (lane & 15);
      const int off = row * 32 + (g ^ ((row >> 1) & 3)) * 8;
      bh[nj] = *(const short8v*)&Bh[off];
      bl[nj] = *(const short8v*)&Bl[off];
    }
#pragma unroll
    for (int mi = 0; mi < 4; ++mi)
#pragma unroll
      for (int nj = 0; nj < 4; ++nj) {
        acc[mi][nj] = __builtin_amdgcn_mfma_f32_16x16x32_bf16(
            ah[mi], bh[nj], acc[mi][nj], 0, 0, 0);
        acc[mi][nj] = __builtin_amdgcn_mfma_f32_16x16x32_bf16(
            ah[mi], bl[nj], acc[mi][nj], 0, 0, 0);
        acc[mi][nj] = __builtin_amdgcn_mfma_f32_16x16x32_bf16(
            al[mi], bh[nj], acc[mi][nj], 0, 0, 0);
      }
  }

  // ---- epilogue: sign bits (f64 fallback near zero) -> ballot -> bitmat ----
#pragma unroll
  for (int mi = 0; mi < 4; ++mi)
#pragma unroll
    for (int nj = 0; nj < 4; ++nj) {
      const int colg = bx * 128 + wc * 64 + nj * 16 + (lane & 15);
      const int rowbase = by * 128 + wr * 64 + mi * 16 + ((lane >> 4) * 4);
      const int col16 = bx * 8 + wc * 4 + nj;
#pragma unroll
      for (int r = 0; r < 4; ++r) {
        const float v = acc[mi][nj][r];
        bool pos = v > 0.f;
        if (fabsf(v) < TAU) {               // rare: exact f64 recompute
          const float* xr = x + (long)(rowbase + r) * 1024;
          const float* wp; int ldw;
          if (colg < 384) { wp = wx + colg; ldw = 384; }
          else            { wp = wv + (colg - 384); ldw = 1024; }
          double s0 = 0, s1 = 0, s2 = 0, s3 = 0;
          for (int d = 0; d < 1024; d += 4) {
            s0 = fma((double)xr[d + 0], (double)wp[(long)(d + 0) * ldw], s0);
            s1 = fma((double)xr[d + 1], (double)wp[(long)(d + 1) * ldw], s1);
            s2 = fma((double)xr[d + 2], (double)wp[(long)(d + 2) * ldw], s2);
            s3 = fma((double)xr[d + 3], (double)wp[(long)(d + 3) * ldw], s3);
          }
          pos = ((s0 + s1) + (s2 + s3)) > 0.0;
        }
        const unsigned long long mask = __ballot(pos);
        if ((lane & 15) == 0)
          bitmat[(long)(rowbase + r) * BITW + col16] =
              (unsigned short)((mask >> (lane & 48)) & 0xFFFFull);
      }
    }
}

// ---------------------------------------------------------------------------
// Kernel 2: bitmat rows -> packed keys (12b) and values (32b), [B,H,T].
// ---------------------------------------------------------------------------
__global__ __launch_bounds__(256) void pack_kernel(
    const unsigned short* __restrict__ bitmat,
    unsigned short* __restrict__ kxg, unsigned int* __restrict__ kvg)
{
  const int gid = blockIdx.x * 256 + threadIdx.x;
  const int row = gid >> 5;                  // b*T + t
  const int h = gid & 31;
  const int b = row >> 12, t = row & (T_ - 1);
  const unsigned short* bp = bitmat + (long)row * BITW;
  const int bitpos = h * NX_;
  const int w0 = bitpos >> 4, off = bitpos & 15;
  const unsigned int v32 = (unsigned int)bp[w0] | ((unsigned int)bp[w0 + 1] << 16);
  const unsigned int key = (v32 >> off) & 0xFFFu;
  const unsigned int val = (unsigned int)bp[24 + 2 * h] |
                           ((unsigned int)bp[25 + 2 * h] << 16);
  const long sidx = ((long)b * H_ + h) * T_ + t;
  kxg[sidx] = (unsigned short)key;
  kvg[sidx] = val;
}

// ---------------------------------------------------------------------------
// Kernel 3: sequential associative-memory scan per (b,h) stream (unchanged).
// ---------------------------------------------------------------------------
#define CH 1024
#define UNR 16

__global__ __launch_bounds__(256) void scan_kernel(
    const unsigned short* __restrict__ kxg,
    const unsigned int* __restrict__ kvg,
    unsigned int* __restrict__ yg)
{
  __shared__ unsigned int table[1 << NX_];
  __shared__ unsigned int kbuf[CH], vbuf[CH], ybuf[CH];
  const int tid = threadIdx.x;
  const long base = (long)blockIdx.x * T_;

#pragma unroll
  for (int i = 0; i < (1 << NX_) / 256; ++i) table[tid + 256 * i] = 0u;

  for (int c = 0; c < T_ / CH; ++c) {
    __syncthreads();
#pragma unroll
    for (int i = 0; i < CH / 256; ++i) {
      kbuf[tid + 256 * i] = kxg[base + c * CH + tid + 256 * i];
      vbuf[tid + 256 * i] = kvg[base + c * CH + tid + 256 * i];
    }
    __syncthreads();
    if (tid == 0) {
      for (int i = 0; i < CH; i += UNR) {
        unsigned int k[UNR], v[UNR], y[UNR];
#pragma unroll
        for (int u = 0; u < UNR; ++u) { k[u] = kbuf[i + u]; v[u] = vbuf[i + u]; }
#pragma unroll
        for (int u = 0; u < UNR; ++u) { y[u] = table[k[u]]; table[k[u]] = v[u]; }
#pragma unroll
        for (int u = 0; u < UNR; ++u) ybuf[i + u] = y[u];
      }
    }
    __syncthreads();
#pragma unroll
    for (int i = 0; i < CH / 256; ++i)
      yg[base + c * CH + tid + 256 * i] = ybuf[tid + 256 * i];
  }
}

// ---------------------------------------------------------------------------
// Kernel 4: expand recalled value bits into f32 embeddings (unchanged).
// ---------------------------------------------------------------------------
__global__ __launch_bounds__(256) void out_kernel(
    const unsigned int* __restrict__ yg,
    const float* __restrict__ e0, const float* __restrict__ e1,
    float* __restrict__ out)
{
  const int tid = threadIdx.x;
  const int bt = blockIdx.x;
  const int b = bt >> 12, t = bt & (T_ - 1);
  const int h = tid >> 3;
  const unsigned int y = yg[((long)b * H_ + h) * T_ + t];
  const int d0 = tid * 4;
  const int vsh = (tid & 7) * 4;
  float4 o;
  o.x = ((y >> (vsh + 0)) & 1) ? e1[d0 + 0] : e0[d0 + 0];
  o.y = ((y >> (vsh + 1)) & 1) ? e1[d0 + 1] : e0[d0 + 1];
  o.z = ((y >> (vsh + 2)) & 1) ? e1[d0 + 2] : e0[d0 + 2];
  o.w = ((y >> (vsh + 3)) & 1) ? e1[d0 + 3] : e0[d0 + 3];
  *(float4*)&out[(long)bt * D_ + d0] = o;
}

// ---------------------------------------------------------------------------
extern "C" void kernel_launch(void* const* d_in, const int* in_sizes, int n_in,
                              void* d_out, int out_size, void* d_ws, size_t ws_size,
                              hipStream_t stream)
{
  const float* x  = (const float*)d_in[0];
  const float* wx = (const float*)d_in[1];
  const float* wv = (const float*)d_in[2];
  const float* e0 = (const float*)d_in[3];
  const float* e1 = (const float*)d_in[4];

  char* ws = (char*)d_ws;
  const size_t MB = 1u << 20;
  unsigned short* Wt_hi  = (unsigned short*)(ws + 0 * MB);   // 2.875 MB
  unsigned short* Wt_lo  = (unsigned short*)(ws + 3 * MB);   // 2.875 MB
  unsigned short* bitmat = (unsigned short*)(ws + 6 * MB);   // 2.875 MB
  unsigned short* kxg    = (unsigned short*)(ws + 9 * MB);   // 1 MB
  unsigned int*   kvg    = (unsigned int*)  (ws + 10 * MB);  // 2 MB
  unsigned int*   yg     = (unsigned int*)  (ws + 12 * MB);  // 2 MB (14 MB total)
  float* out = (float*)d_out;

  hipLaunchKernelGGL(wsplit_kernel, dim3((NCOL / 64) * 16), dim3(256), 0, stream,
                     wx, wv, Wt_hi, Wt_lo);
  hipLaunchKernelGGL(gemm_kernel, dim3(11 * 128), dim3(256), 0, stream,
                     x, Wt_hi, Wt_lo, wx, wv, bitmat);
  hipLaunchKernelGGL(pack_kernel, dim3(2048), dim3(256), 0, stream,
                     bitmat, kxg, kvg);
  hipLaunchKernelGGL(scan_kernel, dim3(B_ * H_), dim3(256), 0, stream,
                     kxg, kvg, yg);
  hipLaunchKernelGGL(out_kernel, dim3(B_ * T_), dim3(256), 0, stream,
                     yg, e0, e1, out);
}

// Round 6
// 878.200 us; speedup vs baseline: 2.0606x; 1.0309x over previous
//
#include <hip/hip_runtime.h>
#include <stdint.h>

#define B_ 4
#define T_ 4096
#define D_ 1024
#define H_ 32
#define NX_ 12
#define NV_ 32
#define NCOL 1408          // 384 wx cols + 1024 wv cols
#define TAU 2e-4f          // |acc| below this -> recompute dot in f64 (~13 sigma)
#define BITW 88            // u16 words per bitmat row (1408/16)

typedef __attribute__((ext_vector_type(8))) short short8v;
typedef __attribute__((ext_vector_type(4))) float floatx4;

static __device__ __forceinline__ unsigned short bf16_rne(float f) {
  unsigned u = __float_as_uint(f);
  return (unsigned short)((u + 0x7FFFu + ((u >> 16) & 1u)) >> 16);
}
static __device__ __forceinline__ float bf16_to_f32(unsigned short h) {
  return __uint_as_float(((unsigned)h) << 16);
}

// MFMA 16x16x32 bf16 fragment k-permutation within each 32-k block:
// stored position p (0..31): group g = p>>3 holds k = {4g..4g+3, 16+4g..4g+19}
// (elems 0-3 = low half, 4-7 = high half of the 8-elem operand). Verified
// (absmax 0.0, round 4).

// ---------------------------------------------------------------------------
// Kernel 0: split W (f32) -> Wt_hi/Wt_lo bf16 [NCOL][1024], transposed and
// k-permuted for direct MFMA fragment loads. (unchanged, verified)
// ---------------------------------------------------------------------------
__global__ __launch_bounds__(256) void wsplit_kernel(
    const float* __restrict__ wx, const float* __restrict__ wv,
    unsigned short* __restrict__ Wt_hi, unsigned short* __restrict__ Wt_lo)
{
  __shared__ float tile[64][65];
  const int tid = threadIdx.x;
  const int cb = blockIdx.x % (NCOL / 64);   // col tile (22)
  const int kb = blockIdx.x / (NCOL / 64);   // k tile (16)
  const int c_local = tid & 63;
  const int c_glob = cb * 64 + c_local;

#pragma unroll
  for (int i = 0; i < 16; ++i) {
    const int k_local = (tid >> 6) + i * 4;
    const int k_glob = kb * 64 + k_local;
    const float v = (c_glob < 384) ? wx[k_glob * 384 + c_glob]
                                   : wv[k_glob * 1024 + (c_glob - 384)];
    tile[k_local][c_local] = v;
  }
  __syncthreads();

#pragma unroll
  for (int i = 0; i < 4; ++i) {
    const int q = (tid >> 6) * 4 + i;        // quad index 0..15
    const int k0 = q * 4;                    // local k base (multiple of 4)
    const int r = k0 & 31;
    const int g = (r < 16) ? (r >> 2) : ((r - 16) >> 2);
    const int half = (r < 16) ? 0 : 1;
    const int p = g * 8 + half * 4;          // permuted position in 32-block
    const long dst = (long)c_glob * 1024 + kb * 64 + (k0 & 32) + p;
    ushort4 hv, lv;
    float f0 = tile[k0 + 0][c_local], f1 = tile[k0 + 1][c_local];
    float f2 = tile[k0 + 2][c_local], f3 = tile[k0 + 3][c_local];
    hv.x = bf16_rne(f0); lv.x = bf16_rne(f0 - bf16_to_f32(hv.x));
    hv.y = bf16_rne(f1); lv.y = bf16_rne(f1 - bf16_to_f32(hv.y));
    hv.z = bf16_rne(f2); lv.z = bf16_rne(f2 - bf16_to_f32(hv.z));
    hv.w = bf16_rne(f3); lv.w = bf16_rne(f3 - bf16_to_f32(hv.w));
    *(ushort4*)&Wt_hi[dst] = hv;
    *(ushort4*)&Wt_lo[dst] = lv;
  }
}

// ---------------------------------------------------------------------------
// Kernel 1: S = x @ [wx|wv] via split-bf16 MFMA; emit sign bits to bitmat.
// m97-style pipelined K-loop: double-buffered LDS, STAGE(t+1) issued before
// compute(t), A-regs prefetched at t for t+2. One barrier per K-step.
// Chunked XCD swizzle: 1408 blocks = 8 XCDs x 176; each XCD owns 16 A-panels.
// ---------------------------------------------------------------------------
__device__ __forceinline__ void a_write(unsigned short* AhB, unsigned short* AlB,
                                        int arow, int ahalf, const float4* f)
{
#pragma unroll
  for (int g = 0; g < 4; ++g) {
    const int sl = g ^ ((arow >> 1) & 3);
    const int idx = arow * 32 + sl * 8 + ahalf * 4;
    ushort4 hv, lv;
    hv.x = bf16_rne(f[g].x); lv.x = bf16_rne(f[g].x - bf16_to_f32(hv.x));
    hv.y = bf16_rne(f[g].y); lv.y = bf16_rne(f[g].y - bf16_to_f32(hv.y));
    hv.z = bf16_rne(f[g].z); lv.z = bf16_rne(f[g].z - bf16_to_f32(hv.z));
    hv.w = bf16_rne(f[g].w); lv.w = bf16_rne(f[g].w - bf16_to_f32(hv.w));
    *(ushort4*)&AhB[idx] = hv;
    *(ushort4*)&AlB[idx] = lv;
  }
}

__global__ __launch_bounds__(256, 2) void gemm_kernel(
    const float* __restrict__ x,
    const unsigned short* __restrict__ Wt_hi,
    const unsigned short* __restrict__ Wt_lo,
    const float* __restrict__ wx, const float* __restrict__ wv,
    unsigned short* __restrict__ bitmat)
{
  __shared__ unsigned short Ah[2][4096], Al[2][4096], Bh[2][4096], Bl[2][4096];

  const int tid = threadIdx.x;
  const int wid = tid >> 6, lane = tid & 63;
  const int wr = wid >> 1, wc = wid & 1;
  // bijective chunked XCD swizzle (1408 = 8 * 176)
  const int sw = (blockIdx.x & 7) * 176 + (blockIdx.x >> 3);
  const int bx = sw % 11;                    // N tile
  const int by = sw / 11;                    // M tile (A panel, 11 sharers/XCD)

  floatx4 acc[4][4];
#pragma unroll
  for (int i = 0; i < 4; ++i)
#pragma unroll
    for (int j = 0; j < 4; ++j) acc[i][j] = (floatx4)0.f;

  const int arow = tid >> 1;                 // A-stage: row 0..127
  const int ahalf = tid & 1;                 // k half (0: k0..15, 1: k16..31)
  const float4* xbase = (const float4*)(x + ((long)(by * 128 + arow)) * 1024);

  // B-stage constants (per-thread): 2 chunks
  int b_c[2]; long b_src0[2];
#pragma unroll
  for (int i = 0; i < 2; ++i) {
    const int c = wid * 64 + i * 256 + lane;
    const int row = c >> 2, sl = c & 3;
    const int g = sl ^ ((row >> 1) & 3);
    b_c[i] = c;
    b_src0[i] = ((long)(bx * 128 + row)) * 1024 + g * 8;
  }

#define STAGE_B(buf, ks)                                                      \
  {                                                                           \
    _Pragma("unroll")                                                         \
    for (int i = 0; i < 2; ++i) {                                             \
      const long src = b_src0[i] + (ks) * 32;                                 \
      __builtin_amdgcn_global_load_lds(                                       \
          (const __attribute__((address_space(1))) unsigned int*)(Wt_hi + src),\
          (__attribute__((address_space(3))) unsigned int*)&Bh[buf][b_c[i] * 8],\
          16, 0, 0);                                                          \
      __builtin_amdgcn_global_load_lds(                                       \
          (const __attribute__((address_space(1))) unsigned int*)(Wt_lo + src),\
          (__attribute__((address_space(3))) unsigned int*)&Bl[buf][b_c[i] * 8],\
          16, 0, 0);                                                          \
    }                                                                         \
  }

  // ---- prologue: fill buffer 0 for ks=0, prefetch A-regs for ks=1 ----
  float4 fA[4], fN[4];
#pragma unroll
  for (int g = 0; g < 4; ++g) fA[g] = xbase[ahalf * 4 + g];          // ks=0
  a_write(Ah[0], Al[0], arow, ahalf, fA);
  STAGE_B(0, 0)
#pragma unroll
  for (int g = 0; g < 4; ++g) fN[g] = xbase[8 + ahalf * 4 + g];      // ks=1
  __syncthreads();

  for (int ks = 0; ks < 32; ++ks) {
    const int cur = ks & 1;

    // ---- STAGE next tile into buf[cur^1] (issued before compute) ----
    if (ks < 31) {
      a_write(Ah[cur ^ 1], Al[cur ^ 1], arow, ahalf, fN);
      STAGE_B(cur ^ 1, ks + 1)
      if (ks < 30) {
#pragma unroll
        for (int g = 0; g < 4; ++g)
          fN[g] = xbase[(ks + 2) * 8 + ahalf * 4 + g];               // ks+2
      }
    }

    // ---- fragment loads (conflict-free b128) + 48 MFMA on buf[cur] ----
    short8v ah[4], al[4], bh[4], bl[4];
    const int g = lane >> 4;
#pragma unroll
    for (int mi = 0; mi < 4; ++mi) {
      const int row = wr * 64 + mi * 16 + (lane & 15);
      const int off = row * 32 + (g ^ ((row >> 1) & 3)) * 8;
      ah[mi] = *(const short8v*)&Ah[cur][off];
      al[mi] = *(const short8v*)&Al[cur][off];
    }
#pragma unroll
    for (int nj = 0; nj < 4; ++nj) {
      const int row = wc * 64 + nj * 16 + (lane & 15);
      const int off = row * 32 + (g ^ ((row >> 1) & 3)) * 8;
      bh[nj] = *(const short8v*)&Bh[cur][off];
      bl[nj] = *(const short8v*)&Bl[cur][off];
    }
#pragma unroll
    for (int mi = 0; mi < 4; ++mi)
#pragma unroll
      for (int nj = 0; nj < 4; ++nj) {
        acc[mi][nj] = __builtin_amdgcn_mfma_f32_16x16x32_bf16(
            ah[mi], bh[nj], acc[mi][nj], 0, 0, 0);
        acc[mi][nj] = __builtin_amdgcn_mfma_f32_16x16x32_bf16(
            ah[mi], bl[nj], acc[mi][nj], 0, 0, 0);
        acc[mi][nj] = __builtin_amdgcn_mfma_f32_16x16x32_bf16(
            al[mi], bh[nj], acc[mi][nj], 0, 0, 0);
      }

    __syncthreads();   // staged data visible; buf[cur] reads complete
  }

  // ---- epilogue: sign bits (f64 fallback near zero) -> ballot -> bitmat ----
#pragma unroll
  for (int mi = 0; mi < 4; ++mi)
#pragma unroll
    for (int nj = 0; nj < 4; ++nj) {
      const int colg = bx * 128 + wc * 64 + nj * 16 + (lane & 15);
      const int rowbase = by * 128 + wr * 64 + mi * 16 + ((lane >> 4) * 4);
      const int col16 = bx * 8 + wc * 4 + nj;
#pragma unroll
      for (int r = 0; r < 4; ++r) {
        const float v = acc[mi][nj][r];
        bool pos = v > 0.f;
        if (fabsf(v) < TAU) {               // rare: exact f64 recompute
          const float* xr = x + (long)(rowbase + r) * 1024;
          const float* wp; int ldw;
          if (colg < 384) { wp = wx + colg; ldw = 384; }
          else            { wp = wv + (colg - 384); ldw = 1024; }
          double s0 = 0, s1 = 0, s2 = 0, s3 = 0;
          for (int d = 0; d < 1024; d += 4) {
            s0 = fma((double)xr[d + 0], (double)wp[(long)(d + 0) * ldw], s0);
            s1 = fma((double)xr[d + 1], (double)wp[(long)(d + 1) * ldw], s1);
            s2 = fma((double)xr[d + 2], (double)wp[(long)(d + 2) * ldw], s2);
            s3 = fma((double)xr[d + 3], (double)wp[(long)(d + 3) * ldw], s3);
          }
          pos = ((s0 + s1) + (s2 + s3)) > 0.0;
        }
        const unsigned long long mask = __ballot(pos);
        if ((lane & 15) == 0)
          bitmat[(long)(rowbase + r) * BITW + col16] =
              (unsigned short)((mask >> (lane & 48)) & 0xFFFFull);
      }
    }
}

// ---------------------------------------------------------------------------
// Kernel 2: bitmat rows -> packed keys (12b) and values (32b), [B,H,T].
// ---------------------------------------------------------------------------
__global__ __launch_bounds__(256) void pack_kernel(
    const unsigned short* __restrict__ bitmat,
    unsigned short* __restrict__ kxg, unsigned int* __restrict__ kvg)
{
  const int gid = blockIdx.x * 256 + threadIdx.x;
  const int row = gid >> 5;                  // b*T + t
  const int h = gid & 31;
  const int b = row >> 12, t = row & (T_ - 1);
  const unsigned short* bp = bitmat + (long)row * BITW;
  const int bitpos = h * NX_;
  const int w0 = bitpos >> 4, off = bitpos & 15;
  const unsigned int v32 = (unsigned int)bp[w0] | ((unsigned int)bp[w0 + 1] << 16);
  const unsigned int key = (v32 >> off) & 0xFFFu;
  const unsigned int val = (unsigned int)bp[24 + 2 * h] |
                           ((unsigned int)bp[25 + 2 * h] << 16);
  const long sidx = ((long)b * H_ + h) * T_ + t;
  kxg[sidx] = (unsigned short)key;
  kvg[sidx] = val;
}

// ---------------------------------------------------------------------------
// Kernel 3: sequential associative-memory scan per (b,h) stream (unchanged).
// ---------------------------------------------------------------------------
#define CH 1024
#define UNR 16

__global__ __launch_bounds__(256) void scan_kernel(
    const unsigned short* __restrict__ kxg,
    const unsigned int* __restrict__ kvg,
    unsigned int* __restrict__ yg)
{
  __shared__ unsigned int table[1 << NX_];
  __shared__ unsigned int kbuf[CH], vbuf[CH], ybuf[CH];
  const int tid = threadIdx.x;
  const long base = (long)blockIdx.x * T_;

#pragma unroll
  for (int i = 0; i < (1 << NX_) / 256; ++i) table[tid + 256 * i] = 0u;

  for (int c = 0; c < T_ / CH; ++c) {
    __syncthreads();
#pragma unroll
    for (int i = 0; i < CH / 256; ++i) {
      kbuf[tid + 256 * i] = kxg[base + c * CH + tid + 256 * i];
      vbuf[tid + 256 * i] = kvg[base + c * CH + tid + 256 * i];
    }
    __syncthreads();
    if (tid == 0) {
      for (int i = 0; i < CH; i += UNR) {
        unsigned int k[UNR], v[UNR], y[UNR];
#pragma unroll
        for (int u = 0; u < UNR; ++u) { k[u] = kbuf[i + u]; v[u] = vbuf[i + u]; }
#pragma unroll
        for (int u = 0; u < UNR; ++u) { y[u] = table[k[u]]; table[k[u]] = v[u]; }
#pragma unroll
        for (int u = 0; u < UNR; ++u) ybuf[i + u] = y[u];
      }
    }
    __syncthreads();
#pragma unroll
    for (int i = 0; i < CH / 256; ++i)
      yg[base + c * CH + tid + 256 * i] = ybuf[tid + 256 * i];
  }
}

// ---------------------------------------------------------------------------
// Kernel 4: expand recalled value bits into f32 embeddings (unchanged).
// ---------------------------------------------------------------------------
__global__ __launch_bounds__(256) void out_kernel(
    const unsigned int* __restrict__ yg,
    const float* __restrict__ e0, const float* __restrict__ e1,
    float* __restrict__ out)
{
  const int tid = threadIdx.x;
  const int bt = blockIdx.x;
  const int b = bt >> 12, t = bt & (T_ - 1);
  const int h = tid >> 3;
  const unsigned int y = yg[((long)b * H_ + h) * T_ + t];
  const int d0 = tid * 4;
  const int vsh = (tid & 7) * 4;
  float4 o;
  o.x = ((y >> (vsh + 0)) & 1) ? e1[d0 + 0] : e0[d0 + 0];
  o.y = ((y >> (vsh + 1)) & 1) ? e1[d0 + 1] : e0[d0 + 1];
  o.z = ((y >> (vsh + 2)) & 1) ? e1[d0 + 2] : e0[d0 + 2];
  o.w = ((y >> (vsh + 3)) & 1) ? e1[d0 + 3] : e0[d0 + 3];
  *(float4*)&out[(long)bt * D_ + d0] = o;
}

// ---------------------------------------------------------------------------
extern "C" void kernel_launch(void* const* d_in, const int* in_sizes, int n_in,
                              void* d_out, int out_size, void* d_ws, size_t ws_size,
                              hipStream_t stream)
{
  const float* x  = (const float*)d_in[0];
  const float* wx = (const float*)d_in[1];
  const float* wv = (const float*)d_in[2];
  const float* e0 = (const float*)d_in[3];
  const float* e1 = (const float*)d_in[4];

  char* ws = (char*)d_ws;
  const size_t MB = 1u << 20;
  unsigned short* Wt_hi  = (unsigned short*)(ws + 0 * MB);   // 2.875 MB
  unsigned short* Wt_lo  = (unsigned short*)(ws + 3 * MB);   // 2.875 MB
  unsigned short* bitmat = (unsigned short*)(ws + 6 * MB);   // 2.875 MB
  unsigned short* kxg    = (unsigned short*)(ws + 9 * MB);   // 1 MB
  unsigned int*   kvg    = (unsigned int*)  (ws + 10 * MB);  // 2 MB
  unsigned int*   yg     = (unsigned int*)  (ws + 12 * MB);  // 2 MB (14 MB total)
  float* out = (float*)d_out;

  hipLaunchKernelGGL(wsplit_kernel, dim3((NCOL / 64) * 16), dim3(256), 0, stream,
                     wx, wv, Wt_hi, Wt_lo);
  hipLaunchKernelGGL(gemm_kernel, dim3(11 * 128), dim3(256), 0, stream,
                     x, Wt_hi, Wt_lo, wx, wv, bitmat);
  hipLaunchKernelGGL(pack_kernel, dim3(2048), dim3(256), 0, stream,
                     bitmat, kxg, kvg);
  hipLaunchKernelGGL(scan_kernel, dim3(B_ * H_), dim3(256), 0, stream,
                     kxg, kvg, yg);
  hipLaunchKernelGGL(out_kernel, dim3(B_ * T_), dim3(256), 0, stream,
                     yg, e0, e1, out);
}